// Round 1
// baseline (2511.868 us; speedup 1.0000x reference)
//
#include <hip/hip_runtime.h>
#include <math.h>

#define BATCH 2
#define NCH 21
#define HH 512
#define WW 512
#define KS 5
#define RAD 2
#define NTAPS 25
#define NUM_ITERS 10

#define TX 64
#define TY 4
#define HALO_W (TX + 2*RAD)   // 68
#define HALO_H (TY + 2*RAD)   // 8
#define HALO_N (HALO_W * HALO_H)  // 544

__device__ __forceinline__ int refl(int i, int n) {
    if (i < 0) i = -i;
    if (i >= n) i = 2*n - 2 - i;
    return i;
}

// ---------------- Kernel A: combined normalized weights, computed once ----------------
// wc[b][tap][y][x] = G2d_norm[tap] + w_rgb[tap]/sum(w_rgb) + w_edge[tap]/sum(w_edge)
__global__ void weights_kernel(const float* __restrict__ image,
                               const float* __restrict__ edges,
                               float* __restrict__ wc) {
    int idx = blockIdx.x * blockDim.x + threadIdx.x;
    if (idx >= BATCH * HH * WW) return;
    int x = idx % WW;
    int y = (idx / WW) % HH;
    int b = idx / (HH * WW);

    // spatial gaussian, sigma_space = 5.0 (normalization cancels in w/sum(w))
    float gs[3];
    gs[0] = 1.0f; gs[1] = expf(-1.0f / 50.0f); gs[2] = expf(-4.0f / 50.0f);
    // blur gaussian, sigma = 0.5, normalized
    float gb[3];
    gb[0] = 1.0f; gb[1] = expf(-2.0f); gb[2] = expf(-8.0f);
    float gbs = gb[0] + 2.0f * (gb[1] + gb[2]);
    gb[0] /= gbs; gb[1] /= gbs; gb[2] /= gbs;

    const size_t plane = (size_t)HH * WW;
    const float* img = image + (size_t)b * 3 * plane;
    const float* edg = edges + (size_t)b * plane;

    float r0 = img[0 * plane + y * WW + x];
    float r1 = img[1 * plane + y * WW + x];
    float r2 = img[2 * plane + y * WW + x];
    float e0 = edg[y * WW + x];

    float wr[NTAPS], we[NTAPS];
    float sr = 0.f, se = 0.f;
#pragma unroll
    for (int dy = 0; dy < KS; dy++) {
        int yy = refl(y + dy - RAD, HH);
#pragma unroll
        for (int dx = 0; dx < KS; dx++) {
            int xx = refl(x + dx - RAD, WW);
            float sp = gs[abs(dy - RAD)] * gs[abs(dx - RAD)];
            float d = fabsf(img[0 * plane + yy * WW + xx] - r0)
                    + fabsf(img[1 * plane + yy * WW + xx] - r1)
                    + fabsf(img[2 * plane + yy * WW + xx] - r2);
            float w1 = sp * expf(-2.0f * d * d);   // inv2sc2 = -0.5/0.25 = -2
            float de = fabsf(edg[yy * WW + xx] - e0);
            float w2 = sp * expf(-2.0f * de * de);
            wr[dy * KS + dx] = w1;
            we[dy * KS + dx] = w2;
            sr += w1;
            se += w2;
        }
    }
    float isr = 1.0f / sr, ise = 1.0f / se;
#pragma unroll
    for (int t = 0; t < NTAPS; t++) {
        int dy = t / KS, dx = t % KS;
        float g2 = gb[abs(dy - RAD)] * gb[abs(dx - RAD)];
        wc[((size_t)b * NTAPS + t) * plane + (size_t)y * WW + x] = g2 + wr[t] * isr + we[t] * ise;
    }
}

// ---------------- Kernel B: initial softmax over channels ----------------
__global__ void softmax_kernel(const float* __restrict__ unary, float* __restrict__ q) {
    int idx = blockIdx.x * blockDim.x + threadIdx.x;
    if (idx >= BATCH * HH * WW) return;
    int p = idx % (HH * WW);
    int b = idx / (HH * WW);
    const size_t plane = (size_t)HH * WW;
    const float* u = unary + (size_t)b * NCH * plane + p;
    float l[NCH];
    float m = -1e30f;
#pragma unroll
    for (int c = 0; c < NCH; c++) { l[c] = u[c * plane]; m = fmaxf(m, l[c]); }
    float s = 0.f;
#pragma unroll
    for (int c = 0; c < NCH; c++) { l[c] = expf(l[c] - m); s += l[c]; }
    float is = 1.0f / s;
    float* qo = q + (size_t)b * NCH * plane + p;
#pragma unroll
    for (int c = 0; c < NCH; c++) qo[c * plane] = l[c] * is;
}

// ---------------- Kernel C: one fused CRF iteration ----------------
// new_q = softmax(unary - f),  f_c = sum_tap wc[tap] * q[c][nbr(tap)]
__global__ __launch_bounds__(256) void crf_iter_kernel(const float* __restrict__ qin,
                                                       const float* __restrict__ unary,
                                                       const float* __restrict__ wc,
                                                       float* __restrict__ qout) {
    __shared__ float tile[HALO_H][HALO_W];
    const int tx = threadIdx.x;      // 0..63
    const int ty = threadIdx.y;      // 0..3
    const int tid = ty * TX + tx;
    const int x0 = blockIdx.x * TX;
    const int y0 = blockIdx.y * TY;
    const int b = blockIdx.z;
    const int x = x0 + tx;
    const int y = y0 + ty;
    const size_t plane = (size_t)HH * WW;

    // per-pixel combined weights, held in registers across the channel loop
    float wcr[NTAPS];
    const float* wp = wc + (size_t)b * NTAPS * plane + (size_t)y * WW + x;
#pragma unroll
    for (int t = 0; t < NTAPS; t++) wcr[t] = wp[t * plane];

    const float* qb = qin + (size_t)b * NCH * plane;
    const float* ub = unary + (size_t)b * NCH * plane + (size_t)y * WW + x;

    float l[NCH];
#pragma unroll
    for (int c = 0; c < NCH; c++) {
        __syncthreads();   // protect tile from previous channel's readers
        const float* qc = qb + (size_t)c * plane;
        for (int i = tid; i < HALO_N; i += 256) {
            int ly = i / HALO_W, lx = i - ly * HALO_W;
            int gy = refl(y0 + ly - RAD, HH);
            int gx = refl(x0 + lx - RAD, WW);
            tile[ly][lx] = qc[gy * WW + gx];
        }
        __syncthreads();
        float f = 0.f;
#pragma unroll
        for (int dy = 0; dy < KS; dy++)
#pragma unroll
            for (int dx = 0; dx < KS; dx++)
                f = fmaf(wcr[dy * KS + dx], tile[ty + dy][tx + dx], f);
        l[c] = ub[c * plane] - f;
    }

    // softmax over channels (in registers)
    float m = l[0];
#pragma unroll
    for (int c = 1; c < NCH; c++) m = fmaxf(m, l[c]);
    float s = 0.f;
#pragma unroll
    for (int c = 0; c < NCH; c++) { l[c] = expf(l[c] - m); s += l[c]; }
    float is = 1.0f / s;
    float* qo = qout + (size_t)b * NCH * plane + (size_t)y * WW + x;
#pragma unroll
    for (int c = 0; c < NCH; c++) qo[c * plane] = l[c] * is;
}

extern "C" void kernel_launch(void* const* d_in, const int* in_sizes, int n_in,
                              void* d_out, int out_size, void* d_ws, size_t ws_size,
                              hipStream_t stream) {
    const float* unary = (const float*)d_in[0];   // B,21,512,512
    const float* image = (const float*)d_in[1];   // B,3,512,512
    const float* edges = (const float*)d_in[2];   // B,512,512
    float* out = (float*)d_out;                   // B,21,512,512
    float* ws = (float*)d_ws;

    float* wc = ws;                                         // B*25*H*W floats
    float* qtmp = ws + (size_t)BATCH * NTAPS * HH * WW;     // B*21*H*W floats

    const int npix = BATCH * HH * WW;
    weights_kernel<<<(npix + 255) / 256, 256, 0, stream>>>(image, edges, wc);
    softmax_kernel<<<(npix + 255) / 256, 256, 0, stream>>>(unary, out);

    dim3 grid(WW / TX, HH / TY, BATCH);
    dim3 block(TX, TY, 1);
    float* qa = out;    // current q
    float* qb = qtmp;   // next q
    for (int it = 0; it < NUM_ITERS; it++) {
        crf_iter_kernel<<<grid, block, 0, stream>>>(qa, unary, wc, qb);
        float* t = qa; qa = qb; qb = t;
    }
    // 10 iterations (even): final result was written to `out` on the last iteration.
}

// Round 2
// 398.678 us; speedup vs baseline: 6.3005x; 6.3005x over previous
//
#include <hip/hip_runtime.h>
#include <math.h>

#define BATCH 2
#define NCH 21
#define CPAD 24            // channels padded to 24 halfs (48 B, 16B-aligned per pixel)
#define HH 512
#define WW 512
#define KS 5
#define RAD 2
#define NTAPS 25
#define NUM_ITERS 10

// iteration-kernel tile
#define TX 32
#define TY 8
#define HX (TX + 2*RAD)    // 36
#define HY (TY + 2*RAD)    // 12
#define HPX (HX * HY)      // 432 halo pixels

typedef _Float16 half8 __attribute__((ext_vector_type(8)));
typedef _Float16 f16;

__device__ __forceinline__ int refl(int i, int n) {
    if (i < 0) i = -i;
    if (i >= n) i = 2*n - 2 - i;
    return i;
}

// ---------------- Kernel A: combined normalized weights (fp16), computed once ----------------
// wc[b][tap][y][x] = G2d_norm[tap] + w_rgb[tap]/sum(w_rgb) + w_edge[tap]/sum(w_edge)
__global__ void weights_kernel(const float* __restrict__ image,
                               const float* __restrict__ edges,
                               f16* __restrict__ wc) {
    int idx = blockIdx.x * blockDim.x + threadIdx.x;
    if (idx >= BATCH * HH * WW) return;
    int x = idx % WW;
    int y = (idx / WW) % HH;
    int b = idx / (HH * WW);

    float gs[3];
    gs[0] = 1.0f; gs[1] = expf(-1.0f / 50.0f); gs[2] = expf(-4.0f / 50.0f);
    float gb[3];
    gb[0] = 1.0f; gb[1] = expf(-2.0f); gb[2] = expf(-8.0f);
    float gbs = gb[0] + 2.0f * (gb[1] + gb[2]);
    gb[0] /= gbs; gb[1] /= gbs; gb[2] /= gbs;

    const size_t plane = (size_t)HH * WW;
    const float* img = image + (size_t)b * 3 * plane;
    const float* edg = edges + (size_t)b * plane;

    float r0 = img[0 * plane + y * WW + x];
    float r1 = img[1 * plane + y * WW + x];
    float r2 = img[2 * plane + y * WW + x];
    float e0 = edg[y * WW + x];

    float wr[NTAPS], we[NTAPS];
    float sr = 0.f, se = 0.f;
#pragma unroll
    for (int dy = 0; dy < KS; dy++) {
        int yy = refl(y + dy - RAD, HH);
#pragma unroll
        for (int dx = 0; dx < KS; dx++) {
            int xx = refl(x + dx - RAD, WW);
            float sp = gs[abs(dy - RAD)] * gs[abs(dx - RAD)];
            float d = fabsf(img[0 * plane + yy * WW + xx] - r0)
                    + fabsf(img[1 * plane + yy * WW + xx] - r1)
                    + fabsf(img[2 * plane + yy * WW + xx] - r2);
            float w1 = sp * expf(-2.0f * d * d);
            float de = fabsf(edg[yy * WW + xx] - e0);
            float w2 = sp * expf(-2.0f * de * de);
            wr[dy * KS + dx] = w1;
            we[dy * KS + dx] = w2;
            sr += w1;
            se += w2;
        }
    }
    float isr = 1.0f / sr, ise = 1.0f / se;
#pragma unroll
    for (int t = 0; t < NTAPS; t++) {
        int dy = t / KS, dx = t % KS;
        float g2 = gb[abs(dy - RAD)] * gb[abs(dx - RAD)];
        wc[((size_t)b * NTAPS + t) * plane + (size_t)y * WW + x]
            = (f16)(g2 + wr[t] * isr + we[t] * ise);
    }
}

// ---------------- Kernel B: initial softmax -> channel-interleaved fp16 q ----------------
__global__ void init_kernel(const float* __restrict__ unary, f16* __restrict__ q) {
    int idx = blockIdx.x * blockDim.x + threadIdx.x;
    if (idx >= BATCH * HH * WW) return;
    int p = idx % (HH * WW);
    int b = idx / (HH * WW);
    const size_t plane = (size_t)HH * WW;
    const float* u = unary + (size_t)b * NCH * plane + p;
    float l[CPAD];
    float m = -1e30f;
#pragma unroll
    for (int c = 0; c < NCH; c++) { l[c] = u[c * plane]; m = fmaxf(m, l[c]); }
    float s = 0.f;
#pragma unroll
    for (int c = 0; c < NCH; c++) { l[c] = expf(l[c] - m); s += l[c]; }
    float is = 1.0f / s;
#pragma unroll
    for (int c = 0; c < NCH; c++) l[c] *= is;
    l[21] = 0.f; l[22] = 0.f; l[23] = 0.f;
    half8* qo = (half8*)(q + ((size_t)b * plane + p) * CPAD);
#pragma unroll
    for (int g = 0; g < 3; g++) {
        half8 v;
#pragma unroll
        for (int k = 0; k < 8; k++) v[k] = (f16)l[g * 8 + k];
        qo[g] = v;
    }
}

// ---------------- Kernel C: one fused CRF iteration ----------------
// new_q = softmax(unary - f),  f_c = sum_tap wc[tap] * q[c][nbr(tap)]
template <bool FINAL>
__global__ __launch_bounds__(256, 4) void crf_iter_kernel(const f16* __restrict__ qin,
                                                          const float* __restrict__ unary,
                                                          const f16* __restrict__ wc,
                                                          void* __restrict__ qout) {
    // 5 float4 sub-tiles (channels 0..19) + scalar tile (channel 20)
    __shared__ __align__(16) float sub[5][HPX][4];   // 34560 B
    __shared__ float s20[HPX];                       // 1728 B

    const int tx = threadIdx.x;      // 0..31
    const int ty = threadIdx.y;      // 0..7
    const int tid = ty * TX + tx;
    const int x0 = blockIdx.x * TX;
    const int y0 = blockIdx.y * TY;
    const int b = blockIdx.z;
    const int x = x0 + tx;
    const int y = y0 + ty;
    const size_t plane = (size_t)HH * WW;

    // ---- stage 12x36 halo, all 21 channels, fp16 global -> fp32 LDS ----
    const f16* qb = qin + (size_t)b * plane * CPAD;
    for (int idx = tid; idx < HPX * 3; idx += TX * TY) {
        int px = idx / 3, h4 = idx - px * 3;        // h4: which 8-channel chunk
        int ly = px / HX, lx = px - ly * HX;
        int gy = refl(y0 + ly - RAD, HH);
        int gx = refl(x0 + lx - RAD, WW);
        half8 v = *(const half8*)(qb + ((size_t)gy * WW + gx) * CPAD + h4 * 8);
        float f0 = (float)v[0], f1 = (float)v[1], f2 = (float)v[2], f3 = (float)v[3];
        float f4 = (float)v[4], f5 = (float)v[5], f6 = (float)v[6], f7 = (float)v[7];
        if (h4 < 2) {
            *(float4*)&sub[2 * h4][px][0]     = make_float4(f0, f1, f2, f3);
            *(float4*)&sub[2 * h4 + 1][px][0] = make_float4(f4, f5, f6, f7);
        } else {
            *(float4*)&sub[4][px][0] = make_float4(f0, f1, f2, f3);
            s20[px] = f4;   // channel 20; 21..23 are padding
        }
    }

    // per-pixel combined weights (fp16 -> fp32), held in registers
    float wcr[NTAPS];
    {
        const f16* wp = wc + (size_t)b * NTAPS * plane + (size_t)y * WW + x;
#pragma unroll
        for (int t = 0; t < NTAPS; t++) wcr[t] = (float)wp[t * plane];
    }

    __syncthreads();

    // ---- 25-tap weighted gather over 21 channels ----
    float acc[NCH];
#pragma unroll
    for (int c = 0; c < NCH; c++) acc[c] = 0.f;

    const int base = ty * HX + tx;
#pragma unroll
    for (int dy = 0; dy < KS; dy++) {
#pragma unroll
        for (int dx = 0; dx < KS; dx++) {
            const float w = wcr[dy * KS + dx];
            const int p = base + dy * HX + dx;
#pragma unroll
            for (int c4 = 0; c4 < 5; c4++) {
                const float4 v = *(const float4*)&sub[c4][p][0];
                acc[c4 * 4 + 0] = fmaf(w, v.x, acc[c4 * 4 + 0]);
                acc[c4 * 4 + 1] = fmaf(w, v.y, acc[c4 * 4 + 1]);
                acc[c4 * 4 + 2] = fmaf(w, v.z, acc[c4 * 4 + 2]);
                acc[c4 * 4 + 3] = fmaf(w, v.w, acc[c4 * 4 + 3]);
            }
            acc[20] = fmaf(w, s20[p], acc[20]);
        }
    }

    // ---- logits + softmax (in registers) ----
    const float* ub = unary + (size_t)b * NCH * plane + (size_t)y * WW + x;
    float l[NCH];
#pragma unroll
    for (int c = 0; c < NCH; c++) l[c] = ub[c * plane] - acc[c];
    float m = l[0];
#pragma unroll
    for (int c = 1; c < NCH; c++) m = fmaxf(m, l[c]);
    float s = 0.f;
#pragma unroll
    for (int c = 0; c < NCH; c++) { l[c] = expf(l[c] - m); s += l[c]; }
    float is = 1.0f / s;
#pragma unroll
    for (int c = 0; c < NCH; c++) l[c] *= is;

    if (FINAL) {
        float* qo = (float*)qout + (size_t)b * NCH * plane + (size_t)y * WW + x;
#pragma unroll
        for (int c = 0; c < NCH; c++) qo[c * plane] = l[c];
    } else {
        half8* qo = (half8*)((f16*)qout + ((size_t)b * plane + (size_t)y * WW + x) * CPAD);
        float lp[CPAD];
#pragma unroll
        for (int c = 0; c < NCH; c++) lp[c] = l[c];
        lp[21] = 0.f; lp[22] = 0.f; lp[23] = 0.f;
#pragma unroll
        for (int g = 0; g < 3; g++) {
            half8 v;
#pragma unroll
            for (int k = 0; k < 8; k++) v[k] = (f16)lp[g * 8 + k];
            qo[g] = v;
        }
    }
}

extern "C" void kernel_launch(void* const* d_in, const int* in_sizes, int n_in,
                              void* d_out, int out_size, void* d_ws, size_t ws_size,
                              hipStream_t stream) {
    const float* unary = (const float*)d_in[0];   // B,21,512,512
    const float* image = (const float*)d_in[1];   // B,3,512,512
    const float* edges = (const float*)d_in[2];   // B,512,512
    float* out = (float*)d_out;                   // B,21,512,512 fp32

    const size_t plane = (size_t)HH * WW;
    char* ws = (char*)d_ws;
    f16* wc = (f16*)ws;                                        // B*25*plane halfs = 26.2 MB
    f16* qA = (f16*)(ws + sizeof(f16) * BATCH * NTAPS * plane);            // 25.2 MB
    f16* qB = qA + (size_t)BATCH * plane * CPAD;                           // 25.2 MB

    const int npix = BATCH * HH * WW;
    weights_kernel<<<(npix + 255) / 256, 256, 0, stream>>>(image, edges, wc);
    init_kernel<<<(npix + 255) / 256, 256, 0, stream>>>(unary, qA);

    dim3 grid(WW / TX, HH / TY, BATCH);
    dim3 block(TX, TY, 1);
    f16* qa = qA;
    f16* qb = qB;
    for (int it = 0; it < NUM_ITERS - 1; it++) {
        crf_iter_kernel<false><<<grid, block, 0, stream>>>(qa, unary, wc, (void*)qb);
        f16* t = qa; qa = qb; qb = t;
    }
    crf_iter_kernel<true><<<grid, block, 0, stream>>>(qa, unary, wc, (void*)out);
}